// Round 6
// baseline (849.098 us; speedup 1.0000x reference)
//
#include <hip/hip_runtime.h>
#include <hip/hip_fp16.h>

#define NB 512   // batch
#define NT 512   // time steps
#define NL 126   // labels
#define NS 128   // states (start=126, end=127)
#define SIGMA 0.0625f   // lagged-normalizer target scale (1/16)

typedef _Float16 h2 __attribute__((ext_vector_type(2)));

static __device__ __forceinline__ int pk_from(float a, float b) {
  return __builtin_bit_cast(int, __builtin_amdgcn_cvt_pkrtz(a, b));
}
// round-to-nearest-even f32->f16 pack (matches the validated u-write rounding)
static __device__ __forceinline__ int pk_rne(float a, float b) {
  h2 p; p.x = (_Float16)a; p.y = (_Float16)b;
  return __builtin_bit_cast(int, p);
}
// guaranteed-packed fp16 ops on int-carried pairs
static __device__ __forceinline__ int pkmul(int a, int b) {
  int d; asm("v_pk_mul_f16 %0, %1, %2" : "=v"(d) : "v"(a), "v"(b)); return d;
}
static __device__ __forceinline__ int pkmax(int a, int b) {
  int d; asm("v_pk_max_f16 %0, %1, %2" : "=v"(d) : "v"(a), "v"(b)); return d;
}
static __device__ __forceinline__ int pkadd(int a, int b) {
  int d; asm("v_pk_add_f16 %0, %1, %2" : "=v"(d) : "v"(a), "v"(b)); return d;
}
// AGPR pin/unpin: force values into the accumulator half of the unified file.
// The register allocator MUST satisfy the "a" constraint -> no scratch spill.
static __device__ __forceinline__ void ag_write(int& ag, int v) {
  asm("v_accvgpr_write_b32 %0, %1" : "=a"(ag) : "v"(v));
}
static __device__ __forceinline__ int ag_read(int ag) {
  int d; asm("v_accvgpr_read_b32 %0, %1" : "=v"(d) : "a"(ag)); return d;
}

// wave64 add-reduce to lane 63, ONE instruction per stage (v_add_f32_dpp).
// Same numeric tree as the validated R0-R5 macro.
#define WAVE_ADD(x) do { \
  asm("v_add_f32_dpp %0, %0, %0 row_shr:1  row_mask:0xf bank_mask:0xf bound_ctrl:0" : "+v"(x)); \
  asm("v_add_f32_dpp %0, %0, %0 row_shr:2  row_mask:0xf bank_mask:0xf bound_ctrl:0" : "+v"(x)); \
  asm("v_add_f32_dpp %0, %0, %0 row_shr:4  row_mask:0xf bank_mask:0xf bound_ctrl:0" : "+v"(x)); \
  asm("v_add_f32_dpp %0, %0, %0 row_shr:8  row_mask:0xf bank_mask:0xf bound_ctrl:0" : "+v"(x)); \
  asm("v_add_f32_dpp %0, %0, %0 row_bcast:15 row_mask:0xa bank_mask:0xf bound_ctrl:0" : "+v"(x)); \
  asm("v_add_f32_dpp %0, %0, %0 row_bcast:31 row_mask:0xc bank_mask:0xf bound_ctrl:0" : "+v"(x)); \
} while (0)

// ONE WAVE PER BATCH ELEMENT — zero barriers (R2/R5 structure, AGPR-fixed).
// Lane l owns columns (2l, 2l+1), all 128 rows. u-vector (128 fp16 = 64
// packed ints) in a 256B LDS buffer: lane writes its packed pair, then all
// lanes broadcast-read the whole vector (same-address b128 = conflict-free;
// per-wave DS queue is in-order -> no barrier, no ping-pong; HW-validated
// absmax 0.0 in R2/R5). R2/R5 both stalled ~2000 cy/step because the
// allocator granted 144 VGPRs for ~215 of demand (tab spilled; occupancy
// attributes don't move the pressure heuristic). Fix: pin all 128 packed
// table entries in AGPRs via "a"-constrained asm — the allocator must comply,
// VGPR demand drops to ~110, zero spill. Bounce cost: one full-rate
// v_accvgpr_read per use (+256 cy/step), hidden across 16 accumulator chains.
__global__ __launch_bounds__(64) __attribute__((amdgpu_waves_per_eu(1, 1)))
void crf_kernel(
    const float* __restrict__ emissions,   // [NB, NT, NL]
    const int*   __restrict__ labels,      // [NB, NT]
    const float* __restrict__ trans,       // [NS, NS]
    float*       __restrict__ out)
{
  const int b   = blockIdx.x;
  const int ln  = threadIdx.x;            // 0..63, single wave
  const int c0  = 2 * ln;                 // columns owned by this lane
  const bool has = (ln < 63);             // lanes whose columns are real labels

  __shared__ __align__(16) int u_lds[64]; // 128 fp16, packed by column pair

  const float* em  = emissions + (size_t)b * NT * NL;
  const int*   lab = labels + (size_t)b * NT;

  // ---- per-column max tau (exact fp32) ----
  float tau0 = -3.0e38f, tau1 = -3.0e38f;
  for (int rr = 0; rr < NS; rr++) {
    float2 tr = *(const float2*)&trans[rr * NS + c0];
    tau0 = fmaxf(tau0, tr.x);
    tau1 = fmaxf(tau1, tr.y);
  }

  // ---- tab[c][k] = rows (2k, 2k+1) of exp(T[.][c]-tau_c), packed fp16,
  //      PINNED IN AGPRs (128 values) ----
  int tAg[64], tBg[64];
  #pragma unroll
  for (int k = 0; k < 64; k++) {
    float2 r0 = *(const float2*)&trans[(2 * k) * NS + c0];
    float2 r1 = *(const float2*)&trans[(2 * k + 1) * NS + c0];
    ag_write(tAg[k], pk_from(__expf(r0.x - tau0), __expf(r1.x - tau0)));
    ag_write(tBg[k], pk_from(__expf(r0.y - tau1), __expf(r1.y - tau1)));
  }

  // ---- gold path partial (8 timesteps per lane) ----
  float realp = 0.f;
  #pragma unroll
  for (int q = 0; q < 8; q++) {
    int t  = ln + q * 64;
    int la = lab[t];
    int na = (t + 1 < NT) ? lab[t + 1] : (NL + 1);
    realp += em[t * NL + la] + trans[la * NS + na];
  }
  if (ln == 0) realp += trans[NL * NS + lab[0]];

  // ---- init: v = delta at start state (col 126 = 1) ----
  u_lds[ln] = (ln == 63) ? pk_rne(1.f, 0.f) : 0;

  // ---- rolling 2-deep emission prefetch (float2 per lane, coalesced) ----
  float2 emc, emn;
  if (has) {
    emc = *(const float2*)&em[c0];
    emn = *(const float2*)&em[NL + c0];
  } else {
    emc.x = emc.y = 0.f; emn.x = emn.y = 0.f;
  }
  const float* emp = em + 2 * NL + c0;    // pointer-bump t+2 prefetch address

  // ---- preload u for step 0 (broadcast reads, in-order after the write) ----
  int4 uu[16];
  {
    const int4* up = (const int4*)u_lds;
    #pragma unroll
    for (int j = 0; j < 16; j++) uu[j] = up[j];
  }

  float Cc = 0.f, Q = 0.f, r = SIGMA;   // r: Z lagged one step (Z_init = 1)

  #pragma unroll 1
  for (int t = 0; t <= NT; t++) {
    // ---- g = exp(obs + tau) from prefetched emission ----
    float obs0, obs1;
    if (t < NT) {
      obs0 = has ? emc.x : -1000.f;     // col 126 (start) gets -1000
      obs1 = has ? emc.y : -1000.f;     // col 127 (end) gets -1000
    } else {
      obs0 = -1000.f;
      obs1 = (ln == 63) ? 0.f : -1000.f; // final step: end state observed
    }
    float g0 = __expf(obs0 + tau0);
    float g1 = __expf(obs1 + tau1);

    // issue t+2 emission prefetch early (global latency hidden under tree)
    float2 ef;
    if (t + 2 < NT && has) ef = *(const float2*)emp;
    else { ef.x = 0.f; ef.y = 0.f; }
    emp += NL;
    emc = emn; emn = ef;

    // ---- critical path: 128 rows x 2 columns, packed fp16, 16 acc chains.
    //      Table entries bounce AGPR->VGPR at full rate (independent reads,
    //      scheduler hoists them ahead of their pkmul). ----
    int h0a=0,h0b=0,h0c=0,h0d=0, s0a=0,s0b=0,s0c=0,s0d=0;
    int h1a=0,h1b=0,h1c=0,h1d=0, s1a=0,s1b=0,s1c=0,s1d=0;
    #pragma unroll
    for (int j = 0; j < 16; j++) {
      int tA0 = ag_read(tAg[4*j+0]);
      int tA1 = ag_read(tAg[4*j+1]);
      int tA2 = ag_read(tAg[4*j+2]);
      int tA3 = ag_read(tAg[4*j+3]);
      int tB0 = ag_read(tBg[4*j+0]);
      int tB1 = ag_read(tBg[4*j+1]);
      int tB2 = ag_read(tBg[4*j+2]);
      int tB3 = ag_read(tBg[4*j+3]);
      int m;
      m = pkmul(uu[j].x, tA0); h0a = pkmax(h0a,m); s0a = pkadd(s0a,m);
      m = pkmul(uu[j].y, tA1); h0b = pkmax(h0b,m); s0b = pkadd(s0b,m);
      m = pkmul(uu[j].z, tA2); h0c = pkmax(h0c,m); s0c = pkadd(s0c,m);
      m = pkmul(uu[j].w, tA3); h0d = pkmax(h0d,m); s0d = pkadd(s0d,m);
      m = pkmul(uu[j].x, tB0); h1a = pkmax(h1a,m); s1a = pkadd(s1a,m);
      m = pkmul(uu[j].y, tB1); h1b = pkmax(h1b,m); s1b = pkadd(s1b,m);
      m = pkmul(uu[j].z, tB2); h1c = pkmax(h1c,m); s1c = pkadd(s1c,m);
      m = pkmul(uu[j].w, tB3); h1d = pkmax(h1d,m); s1d = pkadd(s1d,m);
    }
    int hv0 = pkmax(pkmax(h0a,h0b), pkmax(h0c,h0d));
    int sv0 = pkadd(pkadd(s0a,s0b), pkadd(s0c,s0d));
    int hv1 = pkmax(pkmax(h1a,h1b), pkmax(h1c,h1d));
    int sv1 = pkadd(pkadd(s1a,s1b), pkadd(s1c,s1d));
    h2 hh0 = __builtin_bit_cast(h2, hv0);
    h2 ss0 = __builtin_bit_cast(h2, sv0);
    h2 hh1 = __builtin_bit_cast(h2, hv1);
    h2 ss1 = __builtin_bit_cast(h2, sv1);
    float h0 = fmaxf(fmaxf((float)hh0.x, (float)hh0.y), 1e-30f);
    float s0 = (float)ss0.x + (float)ss0.y;
    float h1 = fmaxf(fmaxf((float)hh1.x, (float)hh1.y), 1e-30f);
    float s1 = (float)ss1.x + (float)ss1.y;

    float w0 = h0 * g0, v0 = w0 * r;
    float w1 = h1 * g1, v1 = w1 * r;

    // ---- write new u, then IMMEDIATELY issue next step's broadcast reads
    //      (per-wave DS queue is in-order; latency hides under the tail) ----
    u_lds[ln] = pk_rne(v0, v1);
    {
      const int4* up = (const int4*)u_lds;
      #pragma unroll
      for (int j = 0; j < 16; j++) uu[j] = up[j];
    }

    // ---- off-path tail: scalars for this step (used next step via lag) ----
    float contrib = s0 * __builtin_amdgcn_rcpf(h0)
                  + s1 * __builtin_amdgcn_rcpf(h1);
    float zz = v0 + v1;
    WAVE_ADD(contrib);
    WAVE_ADD(zz);
    float S = __shfl(contrib, 63);
    float Z = __shfl(zz, 63);
    Cc += __logf(S);
    Q  += __logf(Z);
    r = SIGMA * __builtin_amdgcn_rcpf(Z);
  }

  // total = Cc + Q + (NT+1)*log(1/SIGMA); one atomic per wave
  WAVE_ADD(realp);
  if (ln == 63) {
    const float CONST = 513.f * 2.772588722f;   // (NT+1) * log 16
    atomicAdd(out, (Cc + Q + CONST) - realp);
  }
}

extern "C" void kernel_launch(void* const* d_in, const int* in_sizes, int n_in,
                              void* d_out, int out_size, void* d_ws, size_t ws_size,
                              hipStream_t stream) {
  const float* em  = (const float*)d_in[0];
  const int*   lab = (const int*)d_in[1];
  const float* tr  = (const float*)d_in[2];
  (void)hipMemsetAsync(d_out, 0, sizeof(float), stream);
  crf_kernel<<<NB, 64, 0, stream>>>(em, lab, tr, (float*)d_out);
}

// Round 7
// 722.127 us; speedup vs baseline: 1.1758x; 1.1758x over previous
//
#include <hip/hip_runtime.h>
#include <hip/hip_fp16.h>

#define NB 512   // batch
#define NT 512   // time steps
#define NL 126   // labels
#define NS 128   // states (start=126, end=127)
#define SIGMA 0.0625f   // lagged-normalizer target scale (1/16)

typedef _Float16 h2 __attribute__((ext_vector_type(2)));

static __device__ __forceinline__ int pk_from(float a, float b) {
  return __builtin_bit_cast(int, __builtin_amdgcn_cvt_pkrtz(a, b));
}
// round-to-nearest-even f32->f16 pack (matches the validated u-write rounding)
static __device__ __forceinline__ int pk_rne(float a, float b) {
  h2 p; p.x = (_Float16)a; p.y = (_Float16)b;
  return __builtin_bit_cast(int, p);
}
// guaranteed-packed fp16 ops on int-carried pairs
static __device__ __forceinline__ int pkmul(int a, int b) {
  int d; asm("v_pk_mul_f16 %0, %1, %2" : "=v"(d) : "v"(a), "v"(b)); return d;
}
static __device__ __forceinline__ int pkmax(int a, int b) {
  int d; asm("v_pk_max_f16 %0, %1, %2" : "=v"(d) : "v"(a), "v"(b)); return d;
}
static __device__ __forceinline__ int pkadd(int a, int b) {
  int d; asm("v_pk_add_f16 %0, %1, %2" : "=v"(d) : "v"(a), "v"(b)); return d;
}
// AGPR pin: force the transition table into the accumulator half of the
// unified file (allocator must satisfy "a") -> VGPR demand ~90, zero spill.
static __device__ __forceinline__ void ag_write(int& ag, int v) {
  asm("v_accvgpr_write_b32 %0, %1" : "=a"(ag) : "v"(v));
}
static __device__ __forceinline__ int ag_read(int ag) {
  int d; asm("v_accvgpr_read_b32 %0, %1" : "=v"(d) : "a"(ag)); return d;
}
// uniform broadcast of lane 63's value via SGPR — no LDS, no lgkm drain
static __device__ __forceinline__ float rdlane63(float x) {
  return __builtin_bit_cast(float,
      __builtin_amdgcn_readlane(__builtin_bit_cast(int, x), 63));
}

// wave64 add-reduce to lane 63, ONE instruction per stage (v_add_f32_dpp).
// Same numeric tree as the validated R0-R6 macro.
#define WAVE_ADD(x) do { \
  asm("v_add_f32_dpp %0, %0, %0 row_shr:1  row_mask:0xf bank_mask:0xf bound_ctrl:0" : "+v"(x)); \
  asm("v_add_f32_dpp %0, %0, %0 row_shr:2  row_mask:0xf bank_mask:0xf bound_ctrl:0" : "+v"(x)); \
  asm("v_add_f32_dpp %0, %0, %0 row_shr:4  row_mask:0xf bank_mask:0xf bound_ctrl:0" : "+v"(x)); \
  asm("v_add_f32_dpp %0, %0, %0 row_shr:8  row_mask:0xf bank_mask:0xf bound_ctrl:0" : "+v"(x)); \
  asm("v_add_f32_dpp %0, %0, %0 row_bcast:15 row_mask:0xa bank_mask:0xf bound_ctrl:0" : "+v"(x)); \
  asm("v_add_f32_dpp %0, %0, %0 row_bcast:31 row_mask:0xc bank_mask:0xf bound_ctrl:0" : "+v"(x)); \
} while (0)

// Light barrier: drain LDS ops for cross-wave visibility, leave global
// prefetch in flight (no cross-wave global traffic in-loop -> safe).
#define LIGHT_BARRIER() do { \
  asm volatile("s_waitcnt lgkmcnt(0)" ::: "memory"); \
  __builtin_amdgcn_s_barrier(); \
  asm volatile("" ::: "memory"); \
} while (0)

// ROW-SPLIT, 2 waves per batch element. Wave w owns rows [64w, 64w+64) of ALL
// 128 columns; lane ln owns columns (2ln, 2ln+1). Per-column h/s finish
// IN-LANE over the wave's 64 rows; only a float4 of partials (h0,s0,h1,s1)
// crosses waves per lane per step (double-buffered, one light barrier). Both
// waves then redundantly compute the IDENTICAL combined h,s,v (fp32 fmax/add
// of the two partials is exact and symmetric), so:
//   - the u vector never crosses waves: each wave writes the whole 256B u
//     buffer (identical bits, benign race) and reads back only its own rows
//     (8x same-address b128); in-order per-wave DS queue -> no barrier
//     (HW-validated in R2/R5/R6, absmax 0.0);
//   - Z, S, realp reductions are wave-internal: DPP reduce + v_readlane
//     broadcast, no LDS round-trip, no shfl lgkm drain.
// tab (64 packed ints) pinned in AGPRs -> VGPR demand ~90, zero spill
// (R3/R4's granted-132-vs-demand-168 spill eliminated by construction).
// Same validated math: full-column tau, fp16 tab/tree, lagged-Z recurrence.
__global__ __launch_bounds__(128) __attribute__((amdgpu_waves_per_eu(1, 1)))
void crf_kernel(
    const float* __restrict__ emissions,   // [NB, NT, NL]
    const int*   __restrict__ labels,      // [NB, NT]
    const float* __restrict__ trans,       // [NS, NS]
    float*       __restrict__ out)
{
  const int b   = blockIdx.x;
  const int tid = threadIdx.x;            // 0..127
  const int wv  = tid >> 6;               // wave 0..1 (row half)
  const int ln  = tid & 63;
  const int c0  = 2 * ln;                 // columns owned by this lane
  const int rb  = 64 * wv;                // first row of this wave's half
  const bool has = (ln < 63);             // lanes whose columns are real labels

  __shared__ __align__(16) int u_lds[64];         // 128 fp16, packed col pairs
  __shared__ __align__(16) float4 part[2][2][64]; // [slot][wave][lane] partials
  __shared__ float fin[2];

  const float* em  = emissions + (size_t)b * NT * NL;
  const int*   lab = labels + (size_t)b * NT;

  // ---- per-column max tau over ALL 128 rows (identical in both waves —
  //      required so the two waves' partials share one scale) ----
  float tau0 = -3.0e38f, tau1 = -3.0e38f;
  for (int rr = 0; rr < NS; rr++) {
    float2 tr = *(const float2*)&trans[rr * NS + c0];
    tau0 = fmaxf(tau0, tr.x);
    tau1 = fmaxf(tau1, tr.y);
  }

  // ---- tab[k] = rows (rb+2k, rb+2k+1) of exp(T[.][c]-tau_c), AGPR-pinned ----
  int tAg[32], tBg[32];
  #pragma unroll
  for (int k = 0; k < 32; k++) {
    float2 r0 = *(const float2*)&trans[(rb + 2 * k) * NS + c0];
    float2 r1 = *(const float2*)&trans[(rb + 2 * k + 1) * NS + c0];
    ag_write(tAg[k], pk_from(__expf(r0.x - tau0), __expf(r1.x - tau0)));
    ag_write(tBg[k], pk_from(__expf(r0.y - tau1), __expf(r1.y - tau1)));
  }

  // ---- gold path partial (4 timesteps per thread) ----
  float realp = 0.f;
  #pragma unroll
  for (int q = 0; q < NT / 128; q++) {
    int t  = tid + q * 128;
    int la = lab[t];
    int na = (t + 1 < NT) ? lab[t + 1] : (NL + 1);
    realp += em[t * NL + la] + trans[la * NS + na];
  }
  if (tid == 0) realp += trans[NL * NS + lab[0]];

  // ---- init u: delta at start state (col 126). Each wave writes the WHOLE
  //      buffer (identical bits), so its own reads need no barrier. ----
  u_lds[ln] = (ln == 63) ? pk_rne(1.f, 0.f) : 0;

  // ---- rolling 2-deep emission prefetch (float2 per lane, coalesced) ----
  float2 emc, emn;
  if (has) {
    emc = *(const float2*)&em[c0];
    emn = *(const float2*)&em[NL + c0];
  } else {
    emc.x = emc.y = 0.f; emn.x = emn.y = 0.f;
  }
  const float* emp = em + 2 * NL + c0;    // pointer-bump t+2 prefetch address

  // ---- preload this wave's u rows (8x same-address b128, in-order) ----
  int4 uu[8];
  {
    const int4* up = (const int4*)u_lds + 8 * wv;
    #pragma unroll
    for (int j = 0; j < 8; j++) uu[j] = up[j];
  }

  float Cc = 0.f, Q = 0.f, r = SIGMA;   // r: Z lagged one step (Z_init = 1)

  #pragma unroll 1
  for (int t = 0; t <= NT; t++) {
    const int sl = t & 1;

    // ---- g = exp(obs + tau) from prefetched emission (off critical path) ----
    float obs0, obs1;
    if (t < NT) {
      obs0 = has ? emc.x : -1000.f;     // col 126 (start) gets -1000
      obs1 = has ? emc.y : -1000.f;     // col 127 (end) gets -1000
    } else {
      obs0 = -1000.f;
      obs1 = (ln == 63) ? 0.f : -1000.f; // final step: end state observed
    }
    float g0 = __expf(obs0 + tau0);
    float g1 = __expf(obs1 + tau1);

    // ---- tree: this wave's 64 rows x 2 columns; 8 accumulator chains ----
    int h0a=0,h0b=0,h0c=0,h0d=0, s0a=0,s0b=0,s0c=0,s0d=0;
    int h1a=0,h1b=0,h1c=0,h1d=0, s1a=0,s1b=0,s1c=0,s1d=0;
    #pragma unroll
    for (int j = 0; j < 8; j++) {
      int tA0 = ag_read(tAg[4*j+0]);
      int tA1 = ag_read(tAg[4*j+1]);
      int tA2 = ag_read(tAg[4*j+2]);
      int tA3 = ag_read(tAg[4*j+3]);
      int tB0 = ag_read(tBg[4*j+0]);
      int tB1 = ag_read(tBg[4*j+1]);
      int tB2 = ag_read(tBg[4*j+2]);
      int tB3 = ag_read(tBg[4*j+3]);
      int m;
      m = pkmul(uu[j].x, tA0); h0a = pkmax(h0a,m); s0a = pkadd(s0a,m);
      m = pkmul(uu[j].y, tA1); h0b = pkmax(h0b,m); s0b = pkadd(s0b,m);
      m = pkmul(uu[j].z, tA2); h0c = pkmax(h0c,m); s0c = pkadd(s0c,m);
      m = pkmul(uu[j].w, tA3); h0d = pkmax(h0d,m); s0d = pkadd(s0d,m);
      m = pkmul(uu[j].x, tB0); h1a = pkmax(h1a,m); s1a = pkadd(s1a,m);
      m = pkmul(uu[j].y, tB1); h1b = pkmax(h1b,m); s1b = pkadd(s1b,m);
      m = pkmul(uu[j].z, tB2); h1c = pkmax(h1c,m); s1c = pkadd(s1c,m);
      m = pkmul(uu[j].w, tB3); h1d = pkmax(h1d,m); s1d = pkadd(s1d,m);
    }
    int hv0 = pkmax(pkmax(h0a,h0b), pkmax(h0c,h0d));
    int sv0 = pkadd(pkadd(s0a,s0b), pkadd(s0c,s0d));
    int hv1 = pkmax(pkmax(h1a,h1b), pkmax(h1c,h1d));
    int sv1 = pkadd(pkadd(s1a,s1b), pkadd(s1c,s1d));
    h2 hh0 = __builtin_bit_cast(h2, hv0);
    h2 ss0 = __builtin_bit_cast(h2, sv0);
    h2 hh1 = __builtin_bit_cast(h2, hv1);
    h2 ss1 = __builtin_bit_cast(h2, sv1);
    float h0p = fmaxf((float)hh0.x, (float)hh0.y);
    float s0p = (float)ss0.x + (float)ss0.y;
    float h1p = fmaxf((float)hh1.x, (float)hh1.y);
    float s1p = (float)ss1.x + (float)ss1.y;

    // ---- cross-wave partial exchange (the ONLY thing that crosses waves) ----
    part[sl][wv][ln] = make_float4(h0p, s0p, h1p, s1p);
    LIGHT_BARRIER();                    // lgkm drain only; vmcnt stays live

    // prefetch t+2 while the partner read is in flight
    float2 ef;
    if (t + 2 < NT && has) ef = *(const float2*)emp;
    else { ef.x = 0.f; ef.y = 0.f; }
    emp += NL;
    emc = emn; emn = ef;

    float4 o = part[sl][wv ^ 1][ln];
    float h0 = fmaxf(fmaxf(h0p, o.x), 1e-30f);
    float s0 = s0p + o.y;
    float h1 = fmaxf(fmaxf(h1p, o.z), 1e-30f);
    float s1 = s1p + o.w;

    float w0 = h0 * g0, v0 = w0 * r;
    float w1 = h1 * g1, v1 = w1 * r;

    // ---- u update: both waves write identical bits; own reads in-order ----
    u_lds[ln] = pk_rne(v0, v1);
    {
      const int4* up = (const int4*)u_lds + 8 * wv;
      #pragma unroll
      for (int j = 0; j < 8; j++) uu[j] = up[j];
    }

    // ---- wave-internal scalars (identical in both waves), no LDS ----
    float contrib = s0 * __builtin_amdgcn_rcpf(h0)
                  + s1 * __builtin_amdgcn_rcpf(h1);
    float zz = v0 + v1;
    WAVE_ADD(contrib);
    WAVE_ADD(zz);
    float S = rdlane63(contrib);
    float Z = rdlane63(zz);
    Cc += __logf(S);
    Q  += __logf(Z);
    r = SIGMA * __builtin_amdgcn_rcpf(Z);
  }

  // total = Cc + Q + (NT+1)*log(1/SIGMA); one atomic per block
  WAVE_ADD(realp);
  if (ln == 63) fin[wv] = realp;
  __syncthreads();
  if (tid == 0) {
    const float CONST = 513.f * 2.772588722f;   // (NT+1) * log 16
    atomicAdd(out, (Cc + Q + CONST) - (fin[0] + fin[1]));
  }
}

extern "C" void kernel_launch(void* const* d_in, const int* in_sizes, int n_in,
                              void* d_out, int out_size, void* d_ws, size_t ws_size,
                              hipStream_t stream) {
  const float* em  = (const float*)d_in[0];
  const int*   lab = (const int*)d_in[1];
  const float* tr  = (const float*)d_in[2];
  (void)hipMemsetAsync(d_out, 0, sizeof(float), stream);
  crf_kernel<<<NB, 128, 0, stream>>>(em, lab, tr, (float*)d_out);
}

// Round 9
// 716.848 us; speedup vs baseline: 1.1845x; 1.0074x over previous
//
#include <hip/hip_runtime.h>
#include <hip/hip_fp16.h>

#define NB 512   // batch
#define NT 512   // time steps
#define NL 126   // labels
#define NS 128   // states (start=126, end=127)
#define SIGMA 0.0625f   // lagged-normalizer target scale (1/16)

typedef _Float16 h2 __attribute__((ext_vector_type(2)));

static __device__ __forceinline__ int pk_from(float a, float b) {
  return __builtin_bit_cast(int, __builtin_amdgcn_cvt_pkrtz(a, b));
}
// guaranteed-packed fp16 ops on int-carried pairs
static __device__ __forceinline__ int pkmul(int a, int b) {
  int d; asm("v_pk_mul_f16 %0, %1, %2" : "=v"(d) : "v"(a), "v"(b)); return d;
}
static __device__ __forceinline__ int pkmax(int a, int b) {
  int d; asm("v_pk_max_f16 %0, %1, %2" : "=v"(d) : "v"(a), "v"(b)); return d;
}
static __device__ __forceinline__ int pkadd(int a, int b) {
  int d; asm("v_pk_add_f16 %0, %1, %2" : "=v"(d) : "v"(a), "v"(b)); return d;
}

// wave64 add-reduce to lane 63, ONE instruction per stage (v_add_f32_dpp).
// Same numeric tree as the validated R0-R7 macro.
#define WAVE_ADD(x) do { \
  asm("v_add_f32_dpp %0, %0, %0 row_shr:1  row_mask:0xf bank_mask:0xf bound_ctrl:0" : "+v"(x)); \
  asm("v_add_f32_dpp %0, %0, %0 row_shr:2  row_mask:0xf bank_mask:0xf bound_ctrl:0" : "+v"(x)); \
  asm("v_add_f32_dpp %0, %0, %0 row_shr:4  row_mask:0xf bank_mask:0xf bound_ctrl:0" : "+v"(x)); \
  asm("v_add_f32_dpp %0, %0, %0 row_shr:8  row_mask:0xf bank_mask:0xf bound_ctrl:0" : "+v"(x)); \
  asm("v_add_f32_dpp %0, %0, %0 row_bcast:15 row_mask:0xa bank_mask:0xf bound_ctrl:0" : "+v"(x)); \
  asm("v_add_f32_dpp %0, %0, %0 row_bcast:31 row_mask:0xc bank_mask:0xf bound_ctrl:0" : "+v"(x)); \
} while (0)

// R3 champion (466us, 2 waves/element, lane owns 1 column x 128 rows) with
// register demand cut UNDER the 132-VGPR grant (R3 demanded ~168 -> ~36 regs
// spilled/rematerialized per step; raising the grant failed in R2/R5/R6, so
// lower the demand instead):
//  - u consumed in TWO halves of 8x int4 (uu live = 32 regs, not 64); a
//    sched_barrier(0) fence stops the compiler hoisting the 2nd-half loads;
//  - the independent scalar block (lagged S/Z logs, r, g, emission prefetch)
//    sits between the fence and tree2, filling the 2nd-half ds_read latency;
//  - unroll 1 (unroll 2 doubled cross-iteration live ranges).
// Math and sync structure are bit-identical to R3 (lag-1 Z — R8 proved lag-2
// numerically fatal; both reductions pre-barrier as in the champion).
__global__ __launch_bounds__(128) __attribute__((amdgpu_waves_per_eu(1, 1)))
void crf_kernel(
    const float* __restrict__ emissions,   // [NB, NT, NL]
    const int*   __restrict__ labels,      // [NB, NT]
    const float* __restrict__ trans,       // [NS, NS]
    float*       __restrict__ out)
{
  const int b   = blockIdx.x;
  const int tid = threadIdx.x;            // 0..127
  const int wv  = tid >> 6;               // wave 0..1
  const int ln  = tid & 63;
  const int col = tid;                    // column 0..127 owned by this lane
  const bool has = (col < NL);

  __shared__ __align__(16) _Float16 u_sh[2][NS];  // ping-pong u buffers
  __shared__ float sPart[2][2];                   // [slot][wave]
  __shared__ float zPart[2][2];
  __shared__ float fin[2];

  const float* em  = emissions + (size_t)b * NT * NL;
  const int*   lab = labels + (size_t)b * NT;

  // ---- per-column max tau (exact fp32) ----
  float tau = -3.0e38f;
  for (int rr = 0; rr < NS; rr++) tau = fmaxf(tau, trans[rr * NS + col]);

  // ---- tab[k] = rows (2k, 2k+1) of exp(T[.][col]-tau), packed fp16 ----
  int tab[64];
  #pragma unroll
  for (int k = 0; k < 64; k++) {
    float t0 = __expf(trans[(2 * k) * NS + col] - tau);
    float t1 = __expf(trans[(2 * k + 1) * NS + col] - tau);
    tab[k] = pk_from(t0, t1);
  }

  // ---- gold path partial (4 timesteps per thread) ----
  float realp = 0.f;
  #pragma unroll
  for (int q = 0; q < NT / 128; q++) {
    int t  = tid + q * 128;
    int la = lab[t];
    int na = (t + 1 < NT) ? lab[t + 1] : (NL + 1);
    realp += em[t * NL + la] + trans[la * NS + na];
  }
  if (tid == 0) realp += trans[NL * NS + lab[0]];

  // ---- init: v = delta at start state (col 126), buffer 0 ----
  u_sh[0][col] = (_Float16)((col == NL) ? 1.f : 0.f);

  // ---- rolling 2-deep emission prefetch (4B per lane, coalesced) ----
  float emc = has ? em[col] : 0.f;
  float emn = has ? em[NL + col] : 0.f;

  float Cc = 0.f, Q = 0.f;
  __syncthreads();

  #pragma unroll 1
  for (int t = 0; t <= NT; t++) {
    const int sl = t & 1;
    const int4* up = (const int4*)u_sh[sl];

    // ---- first half of u (8x same-address b128 broadcast) + tree1 ----
    int4 uu[8];
    #pragma unroll
    for (int j = 0; j < 8; j++) uu[j] = up[j];

    int ha = 0, hb = 0, hcc = 0, hd = 0;
    int sa = 0, sb = 0, scc = 0, sd = 0;
    #pragma unroll
    for (int j = 0; j < 8; j++) {
      int m;
      m = pkmul(uu[j].x, tab[4*j+0]); ha  = pkmax(ha,  m); sa  = pkadd(sa,  m);
      m = pkmul(uu[j].y, tab[4*j+1]); hb  = pkmax(hb,  m); sb  = pkadd(sb,  m);
      m = pkmul(uu[j].z, tab[4*j+2]); hcc = pkmax(hcc, m); scc = pkadd(scc, m);
      m = pkmul(uu[j].w, tab[4*j+3]); hd  = pkmax(hd,  m); sd  = pkadd(sd,  m);
    }

    // fence: 2nd-half loads must NOT be hoisted above tree1 (would put 16
    // int4 live at once and re-create the spill this round exists to kill)
    __builtin_amdgcn_sched_barrier(0);

    // ---- second half of u loads; their ~120cy latency is filled by the
    //      independent scalar block below ----
    #pragma unroll
    for (int j = 0; j < 8; j++) uu[j] = up[8 + j];

    // ---- lagged scalars from step t-1 (slot t&1) — off critical path ----
    float r;
    if (t > 0) {
      float S = sPart[sl][0] + sPart[sl][1];
      float Z = zPart[sl][0] + zPart[sl][1];
      Cc += __logf(S);
      Q  += __logf(Z);
      r = SIGMA * __builtin_amdgcn_rcpf(Z);
    } else {
      r = SIGMA;                       // Z(init) = 1
    }

    // g = exp(obs + tau) from prefetched emission
    float obs;
    if (t < NT) obs = has ? emc : -1000.f;
    else        obs = (col == NL + 1) ? 0.f : -1000.f;
    float g = __expf(obs + tau);

    // issue t+2 emission prefetch (in flight across the barrier)
    float ef = (t + 2 < NT && has) ? em[(t + 2) * NL + col] : 0.f;
    emc = emn; emn = ef;

    // ---- tree2: rows 64..127 ----
    #pragma unroll
    for (int j = 0; j < 8; j++) {
      int m;
      m = pkmul(uu[j].x, tab[32+4*j+0]); ha  = pkmax(ha,  m); sa  = pkadd(sa,  m);
      m = pkmul(uu[j].y, tab[32+4*j+1]); hb  = pkmax(hb,  m); sb  = pkadd(sb,  m);
      m = pkmul(uu[j].z, tab[32+4*j+2]); hcc = pkmax(hcc, m); scc = pkadd(scc, m);
      m = pkmul(uu[j].w, tab[32+4*j+3]); hd  = pkmax(hd,  m); sd  = pkadd(sd,  m);
    }
    int hv = pkmax(pkmax(ha, hb), pkmax(hcc, hd));
    int sv = pkadd(pkadd(sa, sb), pkadd(scc, sd));
    h2 hh = __builtin_bit_cast(h2, hv);
    h2 ss = __builtin_bit_cast(h2, sv);
    float h = fmaxf(fmaxf((float)hh.x, (float)hh.y), 1e-30f);
    float s = (float)ss.x + (float)ss.y;

    float w = h * g;
    float v = w * r;
    u_sh[sl ^ 1][col] = (_Float16)v;   // single b16 write per lane

    // ---- reductions for next step's lagged scalars (champion placement) ----
    float contrib = s * __builtin_amdgcn_rcpf(h);
    float zz = v;
    WAVE_ADD(contrib);
    WAVE_ADD(zz);
    if (ln == 63) {
      sPart[sl ^ 1][wv] = contrib;
      zPart[sl ^ 1][wv] = zz;
    }
    __syncthreads();                   // the ONLY barrier per step (2 waves)
  }

  // ---- final scalars of step NT (slot (NT+1)&1 = 1) ----
  {
    float S = sPart[1][0] + sPart[1][1];
    float Z = zPart[1][0] + zPart[1][1];
    Cc += __logf(S);
    Q  += __logf(Z);
  }

  // total = Cc + Q + (NT+1)*log(1/SIGMA); one atomic per block
  WAVE_ADD(realp);
  if (ln == 63) fin[wv] = realp;
  __syncthreads();
  if (tid == 0) {
    const float CONST = 513.f * 2.772588722f;   // (NT+1) * log 16
    atomicAdd(out, (Cc + Q + CONST) - (fin[0] + fin[1]));
  }
}

extern "C" void kernel_launch(void* const* d_in, const int* in_sizes, int n_in,
                              void* d_out, int out_size, void* d_ws, size_t ws_size,
                              hipStream_t stream) {
  const float* em  = (const float*)d_in[0];
  const int*   lab = (const int*)d_in[1];
  const float* tr  = (const float*)d_in[2];
  (void)hipMemsetAsync(d_out, 0, sizeof(float), stream);
  crf_kernel<<<NB, 128, 0, stream>>>(em, lab, tr, (float*)d_out);
}